// Round 5
// baseline (6708.643 us; speedup 1.0000x reference)
//
#include <hip/hip_runtime.h>

typedef __attribute__((ext_vector_type(4))) float f32x4;
typedef __attribute__((ext_vector_type(8))) short short8;
typedef __attribute__((ext_vector_type(4))) short short4_t;

__device__ __forceinline__ short f2bf(float f) {
  unsigned u = __float_as_uint(f);
  u += 0x7fffu + ((u >> 16) & 1u);   // round-to-nearest-even
  return (short)(u >> 16);
}

__device__ __forceinline__ float tanh_fast(float x) {
  float e = __expf(2.0f * x);
  return 1.0f - __fdividef(2.0f, e + 1.0f);
}

// ---------------------------------------------------------------- convert W,U -> bf16
__global__ __launch_bounds__(256) void convert_wu(
    const float* __restrict__ W, const float* __restrict__ U,
    short* __restrict__ Wb, short* __restrict__ Ub) {
  int i = blockIdx.x * 256 + threadIdx.x;
  if (i < 65536) {
    f32x4 v = ((const f32x4*)W)[i];
    short4_t s;
    s.x = f2bf(v.x); s.y = f2bf(v.y); s.z = f2bf(v.z); s.w = f2bf(v.w);
    ((short4_t*)Wb)[i] = s;
  } else if (i < 98304) {
    int k = i - 65536;
    f32x4 v = ((const f32x4*)U)[k];
    short4_t s;
    s.x = f2bf(v.x); s.y = f2bf(v.y); s.z = f2bf(v.z); s.w = f2bf(v.w);
    ((short4_t*)Ub)[k] = s;
  }
}

// ---------------------------------------------------------------- xu = x @ U^T  (bf16 MFMA)
__global__ __launch_bounds__(256) void xu_gemm(
    const float* __restrict__ x, const short* __restrict__ Ub,
    float* __restrict__ out) {
  __shared__ __attribute__((aligned(16))) short a_lds[128][272];
  __shared__ __attribute__((aligned(16))) short b_lds[128][272];
  const int tid = threadIdx.x;
  const int mb = blockIdx.x >> 2;
  const int nb = blockIdx.x & 3;

  const float* xb = x + (size_t)mb * (128 * 256);
  for (int c = 0; c < 32; ++c) {
    int idx = c * 256 + tid;
    int r = idx >> 6, c4 = idx & 63;
    f32x4 v = ((const f32x4*)xb)[idx];
    short4_t s;
    s.x = f2bf(v.x); s.y = f2bf(v.y); s.z = f2bf(v.z); s.w = f2bf(v.w);
    *(short4_t*)&a_lds[r][c4 * 4] = s;
  }
  const short* ub = Ub + nb * (128 * 256);
  for (int c = 0; c < 16; ++c) {
    int idx = c * 256 + tid;
    int r = idx >> 5, ch = idx & 31;
    *(short8*)&b_lds[r][ch * 8] = ((const short8*)ub)[idx];
  }
  __syncthreads();

  const int lane = tid & 63, wave = tid >> 6;
  const int wr = wave >> 1, wc = wave & 1;
  const int lr = lane & 15, lk = lane >> 4;
  const f32x4 zero = {0.f, 0.f, 0.f, 0.f};
  f32x4 acc[4][4];
  #pragma unroll
  for (int mt = 0; mt < 4; ++mt)
    #pragma unroll
    for (int nt = 0; nt < 4; ++nt) acc[mt][nt] = zero;

  #pragma unroll
  for (int kt = 0; kt < 8; ++kt) {
    const int k = kt * 32 + lk * 8;
    short8 a[4], b[4];
    #pragma unroll
    for (int mt = 0; mt < 4; ++mt)
      a[mt] = *(const short8*)&a_lds[wr * 64 + mt * 16 + lr][k];
    #pragma unroll
    for (int nt = 0; nt < 4; ++nt)
      b[nt] = *(const short8*)&b_lds[wc * 64 + nt * 16 + lr][k];
    #pragma unroll
    for (int mt = 0; mt < 4; ++mt)
      #pragma unroll
      for (int nt = 0; nt < 4; ++nt)
        acc[mt][nt] = __builtin_amdgcn_mfma_f32_16x16x32_bf16(a[mt], b[nt], acc[mt][nt], 0, 0, 0);
  }

  #pragma unroll
  for (int mt = 0; mt < 4; ++mt)
    #pragma unroll
    for (int nt = 0; nt < 4; ++nt)
      #pragma unroll
      for (int q = 0; q < 4; ++q) {
        int row = mb * 128 + wr * 64 + mt * 16 + lk * 4 + q;
        int col = nb * 128 + wc * 64 + nt * 16 + lr;
        out[(size_t)row * 512 + col] = acc[mt][nt][q];
      }
}

// ---------------------------------------------------------------- recurrence scan
// 16 blocks = 4 batch-groups x 4 j-slices (128 cols each). Each wave owns 16
// output cols; its W slice (16 cols x 512 k = 64 VGPR) lives in registers —
// the feasible form of register-resident W (replicated per group; a single
// CU cannot hold 512KB = its entire register file, per R1-R4 post-mortems).
// Per step: read full tanh(h) [16x512 bf16] from a double-buffered global
// exchange buffer as MFMA A-frags, 16 chained MFMA/wave, update h, write own
// tanh slice, then a 4-block sense-free epoch barrier through L2/L3.
__global__ __launch_bounds__(512, 2) void rnn_scan(
    const short* __restrict__ Wb, float* __restrict__ out,
    short* __restrict__ ex, unsigned* __restrict__ bar) {
  const int tid = threadIdx.x;
  const int g = blockIdx.x >> 2;        // batch group 0..3 (rows 16g..16g+15)
  const int s = blockIdx.x & 3;         // j-slice 0..3 (cols 128s..)
  const int lane = tid & 63, wave = tid >> 6;
  const int lr = lane & 15, lk = lane >> 4;
  const int jc = s * 128 + wave * 16 + lr;     // this lane's output column

  // W fragments: wreg[kt] = W[jc][kt*32 + lk*8 .. +8]  (B-frag layout)
  short8 wreg[16];
  #pragma unroll
  for (int kt = 0; kt < 16; ++kt)
    wreg[kt] = *(const short8*)(Wb + jc * 512 + kt * 32 + lk * 8);

  float h[4] = {0.f, 0.f, 0.f, 0.f};
  const size_t rbase = (size_t)(g * 16 + lk * 4) * 524288 + jc;  // out index base

  unsigned* cnt = bar + g * 64;         // 256B per group, cnt/epoch 128B apart
  unsigned* ep  = bar + g * 64 + 32;
  short* ex0 = ex + g * 8192;           // parity-0 buffer for this group [16][512]
  short* ex1 = ex + 32768 + g * 8192;   // parity-1

  for (int t = 0; t < 1024; ++t) {
    // acc <- xu_t (read from out; overwritten with h below)
    f32x4 acc;
    const float* px = out + rbase + (size_t)t * 512;
    #pragma unroll
    for (int q = 0; q < 4; ++q) acc[q] = px[(size_t)q * 524288];

    if (t > 0) {
      const short* pa = (t & 1) ? ex1 : ex0;   // tanh(h_t), written at iter t-1
      f32x4 acc2 = {0.f, 0.f, 0.f, 0.f};
      #pragma unroll
      for (int kt = 0; kt < 16; kt += 2) {     // 2 chains to break MFMA dep latency
        short8 a0 = *(const short8*)(pa + lr * 512 + kt * 32 + lk * 8);
        short8 a1 = *(const short8*)(pa + lr * 512 + (kt + 1) * 32 + lk * 8);
        acc  = __builtin_amdgcn_mfma_f32_16x16x32_bf16(a0, wreg[kt],     acc,  0, 0, 0);
        acc2 = __builtin_amdgcn_mfma_f32_16x16x32_bf16(a1, wreg[kt + 1], acc2, 0, 0, 0);
      }
      #pragma unroll
      for (int q = 0; q < 4; ++q) acc[q] += acc2[q];
    }

    // h' = 0.9h + 0.1acc; store h to out (in place over xu_t); tanh -> exchange
    float* po = out + rbase + (size_t)t * 512;
    short* pw = ((t & 1) ? ex0 : ex1) + jc;    // parity (t+1)&1
    #pragma unroll
    for (int q = 0; q < 4; ++q) {
      float v = 0.9f * h[q] + 0.1f * acc[q];
      h[q] = v;
      po[(size_t)q * 524288] = v;
      if (t < 1023) pw[(lk * 4 + q) * 512] = f2bf(tanh_fast(v));
    }

    if (t < 1023) {
      __syncthreads();                         // drains all waves' stores (vmcnt0 before s_barrier)
      if (tid == 0) {
        __threadfence();                       // release: flush L2 to coherence point
        unsigned old = __hip_atomic_fetch_add(cnt, 1u, __ATOMIC_RELAXED, __HIP_MEMORY_SCOPE_AGENT);
        if (old == 3u) {                       // last of 4: reset count, publish epoch
          __hip_atomic_store(cnt, 0u, __ATOMIC_RELAXED, __HIP_MEMORY_SCOPE_AGENT);
          __hip_atomic_store(ep, (unsigned)(t + 1), __ATOMIC_RELEASE, __HIP_MEMORY_SCOPE_AGENT);
        } else {
          while (__hip_atomic_load(ep, __ATOMIC_RELAXED, __HIP_MEMORY_SCOPE_AGENT) < (unsigned)(t + 1)) {}
        }
        __threadfence();                       // acquire: invalidate stale L1/L2 lines
      }
      __syncthreads();
    }
  }
}

// ----------------------------------------------------------------
extern "C" void kernel_launch(void* const* d_in, const int* in_sizes, int n_in,
                              void* d_out, int out_size, void* d_ws, size_t ws_size,
                              hipStream_t stream) {
  (void)in_sizes; (void)n_in; (void)out_size; (void)ws_size;
  const float* x = (const float*)d_in[0];   // [64,1024,256]
  const float* W = (const float*)d_in[1];   // [512,512]
  const float* U = (const float*)d_in[2];   // [512,256]
  float* out = (float*)d_out;               // [64,1024,512]
  short* Wb = (short*)d_ws;                 // 512KB bf16 W
  short* Ub = Wb + 262144;                  // 256KB bf16 U
  short* ex = Ub + 131072;                  // 128KB exchange: [2][4][16][512] bf16
  unsigned* bar = (unsigned*)(ex + 65536);  // 1KB barrier state (4 groups x 256B)

  hipMemsetAsync((void*)bar, 0, 1024, stream);
  convert_wu<<<384, 256, 0, stream>>>(W, U, Wb, Ub);
  xu_gemm<<<2048, 256, 0, stream>>>(x, Ub, out);
  rnn_scan<<<16, 512, 0, stream>>>(Wb, out, ex, bar);
}

// Round 6
// 3184.181 us; speedup vs baseline: 2.1069x; 2.1069x over previous
//
#include <hip/hip_runtime.h>

typedef __attribute__((ext_vector_type(4))) float f32x4;
typedef __attribute__((ext_vector_type(8))) short short8;
typedef __attribute__((ext_vector_type(4))) short short4_t;

__device__ __forceinline__ short f2bf(float f) {
  unsigned u = __float_as_uint(f);
  u += 0x7fffu + ((u >> 16) & 1u);   // round-to-nearest-even
  return (short)(u >> 16);
}

__device__ __forceinline__ float tanh_fast(float x) {
  float e = __expf(2.0f * x);
  return 1.0f - __fdividef(2.0f, e + 1.0f);
}

// ---------------------------------------------------------------- convert W,U -> bf16
__global__ __launch_bounds__(256) void convert_wu(
    const float* __restrict__ W, const float* __restrict__ U,
    short* __restrict__ Wb, short* __restrict__ Ub) {
  int i = blockIdx.x * 256 + threadIdx.x;
  if (i < 65536) {
    f32x4 v = ((const f32x4*)W)[i];
    short4_t s;
    s.x = f2bf(v.x); s.y = f2bf(v.y); s.z = f2bf(v.z); s.w = f2bf(v.w);
    ((short4_t*)Wb)[i] = s;
  } else if (i < 98304) {
    int k = i - 65536;
    f32x4 v = ((const f32x4*)U)[k];
    short4_t s;
    s.x = f2bf(v.x); s.y = f2bf(v.y); s.z = f2bf(v.z); s.w = f2bf(v.w);
    ((short4_t*)Ub)[k] = s;
  }
}

// ---------------------------------------------------------------- xu = x @ U^T  (bf16 MFMA)
__global__ __launch_bounds__(256) void xu_gemm(
    const float* __restrict__ x, const short* __restrict__ Ub,
    float* __restrict__ out) {
  __shared__ __attribute__((aligned(16))) short a_lds[128][272];
  __shared__ __attribute__((aligned(16))) short b_lds[128][272];
  const int tid = threadIdx.x;
  const int mb = blockIdx.x >> 2;
  const int nb = blockIdx.x & 3;

  const float* xb = x + (size_t)mb * (128 * 256);
  for (int c = 0; c < 32; ++c) {
    int idx = c * 256 + tid;
    int r = idx >> 6, c4 = idx & 63;
    f32x4 v = ((const f32x4*)xb)[idx];
    short4_t s;
    s.x = f2bf(v.x); s.y = f2bf(v.y); s.z = f2bf(v.z); s.w = f2bf(v.w);
    *(short4_t*)&a_lds[r][c4 * 4] = s;
  }
  const short* ub = Ub + nb * (128 * 256);
  for (int c = 0; c < 16; ++c) {
    int idx = c * 256 + tid;
    int r = idx >> 5, ch = idx & 31;
    *(short8*)&b_lds[r][ch * 8] = ((const short8*)ub)[idx];
  }
  __syncthreads();

  const int lane = tid & 63, wave = tid >> 6;
  const int wr = wave >> 1, wc = wave & 1;
  const int lr = lane & 15, lk = lane >> 4;
  const f32x4 zero = {0.f, 0.f, 0.f, 0.f};
  f32x4 acc[4][4];
  #pragma unroll
  for (int mt = 0; mt < 4; ++mt)
    #pragma unroll
    for (int nt = 0; nt < 4; ++nt) acc[mt][nt] = zero;

  #pragma unroll
  for (int kt = 0; kt < 8; ++kt) {
    const int k = kt * 32 + lk * 8;
    short8 a[4], b[4];
    #pragma unroll
    for (int mt = 0; mt < 4; ++mt)
      a[mt] = *(const short8*)&a_lds[wr * 64 + mt * 16 + lr][k];
    #pragma unroll
    for (int nt = 0; nt < 4; ++nt)
      b[nt] = *(const short8*)&b_lds[wc * 64 + nt * 16 + lr][k];
    #pragma unroll
    for (int mt = 0; mt < 4; ++mt)
      #pragma unroll
      for (int nt = 0; nt < 4; ++nt)
        acc[mt][nt] = __builtin_amdgcn_mfma_f32_16x16x32_bf16(a[mt], b[nt], acc[mt][nt], 0, 0, 0);
  }

  #pragma unroll
  for (int mt = 0; mt < 4; ++mt)
    #pragma unroll
    for (int nt = 0; nt < 4; ++nt)
      #pragma unroll
      for (int q = 0; q < 4; ++q) {
        int row = mb * 128 + wr * 64 + mt * 16 + lk * 4 + q;
        int col = nb * 128 + wc * 64 + nt * 16 + lr;
        out[(size_t)row * 512 + col] = acc[mt][nt][q];
      }
}

// ---------------------------------------------------------------- recurrence scan
// R2 structure (4 blocks x 512 thr, no cross-block sync) + the register-budget
// fix: amdgpu_waves_per_eu(2,2) pins occupancy at exactly 2 waves/EU -> 256
// VGPR budget per wave. R1/R2's VGPR_Count~124 showed the allocator behaved
// as if capped at ~128 regs, so the 192-reg W array ALWAYS spilled; reloads
// were L2 hits (~2000 cyc/step through L1), invisible in FETCH_SIZE. With the
// budget legal, W k in [0,384) genuinely lives in 192 VGPRs; k in [384,512)
// in LDS (128KB). MFMA floor: 512 MFMA/CU/step x 4.85cyc = 2483 cyc ~ 1.03us.
__global__ __launch_bounds__(512)
__attribute__((amdgpu_waves_per_eu(2, 2)))
void rnn_scan(const short* __restrict__ Wb, float* __restrict__ out) {
  __shared__ __attribute__((aligned(16))) short w_lds[512][136];  // k 384..512
  __shared__ __attribute__((aligned(16))) short a_lds[16][520];   // tanh(h) bf16
  const int tid = threadIdx.x;
  const int blk = blockIdx.x;
  const int lane = tid & 63, wave = tid >> 6;
  const int j0 = wave * 64;
  const int lr = lane & 15, lk = lane >> 4;

  // register-resident W fragments: B[k][j] = W[j][k], lane holds 8 contiguous k
  short8 wreg[4][12];
  #pragma unroll
  for (int jt = 0; jt < 4; ++jt) {
    const short* wrow = Wb + (j0 + jt * 16 + lr) * 512 + lk * 8;
    #pragma unroll
    for (int kt = 0; kt < 12; ++kt) {
      wreg[jt][kt] = *(const short8*)(wrow + kt * 32);
      asm volatile("" : "+v"(wreg[jt][kt]));   // block remat/sink of the load
    }
  }

  // LDS-resident W slice (k in [384,512))
  for (int c = 0; c < 16; ++c) {
    int idx = c * 512 + tid;
    int j = idx >> 4, ch = idx & 15;
    *(short8*)&w_lds[j][ch * 8] = *(const short8*)(Wb + j * 512 + 384 + ch * 8);
  }

  float h[4][4];
  #pragma unroll
  for (int jt = 0; jt < 4; ++jt)
    #pragma unroll
    for (int q = 0; q < 4; ++q) h[jt][q] = 0.f;

  const size_t base = (size_t)(blk * 16 + lk * 4) * 524288 + j0 + lr;
  __syncthreads();

  f32x4 acc[4];
  // prologue: acc <- xu[t=0]
  {
    const float* p = out + base;
    #pragma unroll
    for (int jt = 0; jt < 4; ++jt)
      #pragma unroll
      for (int q = 0; q < 4; ++q)
        acc[jt][q] = p[(size_t)q * 524288 + jt * 16];
  }

  for (int t = 0; t < 1024; ++t) {
    // A = tanh(h) -> bf16 staging
    #pragma unroll
    for (int jt = 0; jt < 4; ++jt)
      #pragma unroll
      for (int q = 0; q < 4; ++q)
        a_lds[lk * 4 + q][j0 + jt * 16 + lr] = f2bf(tanh_fast(h[jt][q]));
    __syncthreads();

    // acc (holds xu_t) += tanh(h) @ W^T
    #pragma unroll
    for (int kt = 0; kt < 16; ++kt) {
      short8 a8 = *(const short8*)&a_lds[lr][kt * 32 + lk * 8];
      if (kt < 12) {
        #pragma unroll
        for (int jt = 0; jt < 4; ++jt)
          acc[jt] = __builtin_amdgcn_mfma_f32_16x16x32_bf16(a8, wreg[jt][kt], acc[jt], 0, 0, 0);
      } else {
        #pragma unroll
        for (int jt = 0; jt < 4; ++jt) {
          short8 b = *(const short8*)&w_lds[j0 + jt * 16 + lr][(kt - 12) * 32 + lk * 8];
          acc[jt] = __builtin_amdgcn_mfma_f32_16x16x32_bf16(a8, b, acc[jt], 0, 0, 0);
        }
      }
    }

    // h' = 0.9*h + 0.1*acc; store in place over xu[t]
    float* po = out + base + (size_t)t * 512;
    #pragma unroll
    for (int jt = 0; jt < 4; ++jt)
      #pragma unroll
      for (int q = 0; q < 4; ++q) {
        float v = 0.9f * h[jt][q] + 0.1f * acc[jt][q];
        h[jt][q] = v;
        po[(size_t)q * 524288 + jt * 16] = v;
      }
    __syncthreads();  // a_lds reads done before next iteration's writes

    // tail: prefetch next step's xu into acc (hides L3 latency)
    int tn = t + 1; if (tn > 1023) tn = 1023;
    const float* pn = out + base + (size_t)tn * 512;
    #pragma unroll
    for (int jt = 0; jt < 4; ++jt)
      #pragma unroll
      for (int q = 0; q < 4; ++q)
        acc[jt][q] = pn[(size_t)q * 524288 + jt * 16];
  }
}

// ----------------------------------------------------------------
extern "C" void kernel_launch(void* const* d_in, const int* in_sizes, int n_in,
                              void* d_out, int out_size, void* d_ws, size_t ws_size,
                              hipStream_t stream) {
  (void)in_sizes; (void)n_in; (void)out_size; (void)ws_size;
  const float* x = (const float*)d_in[0];
  const float* W = (const float*)d_in[1];
  const float* U = (const float*)d_in[2];
  float* out = (float*)d_out;
  short* Wb = (short*)d_ws;
  short* Ub = Wb + 512 * 512;

  convert_wu<<<384, 256, 0, stream>>>(W, U, Wb, Ub);
  xu_gemm<<<2048, 256, 0, stream>>>(x, Ub, out);
  rnn_scan<<<4, 512, 0, stream>>>(Wb, out);
}

// Round 7
// 3158.553 us; speedup vs baseline: 2.1240x; 1.0081x over previous
//
#include <hip/hip_runtime.h>

typedef __attribute__((ext_vector_type(4))) float f32x4;
typedef __attribute__((ext_vector_type(8))) short short8;
typedef __attribute__((ext_vector_type(4))) short short4_t;

__device__ __forceinline__ short f2bf(float f) {
  unsigned u = __float_as_uint(f);
  u += 0x7fffu + ((u >> 16) & 1u);   // round-to-nearest-even
  return (short)(u >> 16);
}

__device__ __forceinline__ float tanh_fast(float x) {
  float e = __expf(2.0f * x);
  return 1.0f - __fdividef(2.0f, e + 1.0f);
}

// ---------------------------------------------------------------- convert W,U -> bf16
__global__ __launch_bounds__(256) void convert_wu(
    const float* __restrict__ W, const float* __restrict__ U,
    short* __restrict__ Wb, short* __restrict__ Ub) {
  int i = blockIdx.x * 256 + threadIdx.x;
  if (i < 65536) {
    f32x4 v = ((const f32x4*)W)[i];
    short4_t s;
    s.x = f2bf(v.x); s.y = f2bf(v.y); s.z = f2bf(v.z); s.w = f2bf(v.w);
    ((short4_t*)Wb)[i] = s;
  } else if (i < 98304) {
    int k = i - 65536;
    f32x4 v = ((const f32x4*)U)[k];
    short4_t s;
    s.x = f2bf(v.x); s.y = f2bf(v.y); s.z = f2bf(v.z); s.w = f2bf(v.w);
    ((short4_t*)Ub)[k] = s;
  }
}

// ---------------------------------------------------------------- xu = x @ U^T  (bf16 MFMA)
__global__ __launch_bounds__(256) void xu_gemm(
    const float* __restrict__ x, const short* __restrict__ Ub,
    float* __restrict__ out) {
  __shared__ __attribute__((aligned(16))) short a_lds[128][272];
  __shared__ __attribute__((aligned(16))) short b_lds[128][272];
  const int tid = threadIdx.x;
  const int mb = blockIdx.x >> 2;
  const int nb = blockIdx.x & 3;

  const float* xb = x + (size_t)mb * (128 * 256);
  for (int c = 0; c < 32; ++c) {
    int idx = c * 256 + tid;
    int r = idx >> 6, c4 = idx & 63;
    f32x4 v = ((const f32x4*)xb)[idx];
    short4_t s;
    s.x = f2bf(v.x); s.y = f2bf(v.y); s.z = f2bf(v.z); s.w = f2bf(v.w);
    *(short4_t*)&a_lds[r][c4 * 4] = s;
  }
  const short* ub = Ub + nb * (128 * 256);
  for (int c = 0; c < 16; ++c) {
    int idx = c * 256 + tid;
    int r = idx >> 5, ch = idx & 31;
    *(short8*)&b_lds[r][ch * 8] = ((const short8*)ub)[idx];
  }
  __syncthreads();

  const int lane = tid & 63, wave = tid >> 6;
  const int wr = wave >> 1, wc = wave & 1;
  const int lr = lane & 15, lk = lane >> 4;
  const f32x4 zero = {0.f, 0.f, 0.f, 0.f};
  f32x4 acc[4][4];
  #pragma unroll
  for (int mt = 0; mt < 4; ++mt)
    #pragma unroll
    for (int nt = 0; nt < 4; ++nt) acc[mt][nt] = zero;

  #pragma unroll
  for (int kt = 0; kt < 8; ++kt) {
    const int k = kt * 32 + lk * 8;
    short8 a[4], b[4];
    #pragma unroll
    for (int mt = 0; mt < 4; ++mt)
      a[mt] = *(const short8*)&a_lds[wr * 64 + mt * 16 + lr][k];
    #pragma unroll
    for (int nt = 0; nt < 4; ++nt)
      b[nt] = *(const short8*)&b_lds[wc * 64 + nt * 16 + lr][k];
    #pragma unroll
    for (int mt = 0; mt < 4; ++mt)
      #pragma unroll
      for (int nt = 0; nt < 4; ++nt)
        acc[mt][nt] = __builtin_amdgcn_mfma_f32_16x16x32_bf16(a[mt], b[nt], acc[mt][nt], 0, 0, 0);
  }

  #pragma unroll
  for (int mt = 0; mt < 4; ++mt)
    #pragma unroll
    for (int nt = 0; nt < 4; ++nt)
      #pragma unroll
      for (int q = 0; q < 4; ++q) {
        int row = mb * 128 + wr * 64 + mt * 16 + lk * 4 + q;
        int col = nb * 128 + wc * 64 + nt * 16 + lr;
        out[(size_t)row * 512 + col] = acc[mt][nt][q];
      }
}

// ---------------------------------------------------------------- recurrence scan
// 4 blocks x 512 thr (8 waves, 1 block/CU). R1-R6 lesson: the allocator hard-
// caps this kernel at 128 VGPRs; 192-reg W residency is impossible. So W is
// split three ways, all within budget:
//   k in [0,64):    32 pinned VGPRs per lane (small pin -> legal, no spill)
//   k in [64,192):  persistent LDS, 128 KB
//   k in [192,512): STREAMED from L2 each step as direct B-frag dwordx4 loads
//                   (read-only, loop-invariant addresses w/ immediate offsets,
//                   depth-2 double buffer interleaved with the MFMAs)
// Streams 320 KB/step/CU from L2 (~2500-2900 cyc) overlapping MFMA 2483 cyc.
__global__ __launch_bounds__(512, 2) void rnn_scan(
    const short* __restrict__ Wb, float* __restrict__ out) {
  __shared__ __attribute__((aligned(16))) short w_lds[512][136];  // k 64..192
  __shared__ __attribute__((aligned(16))) short a_lds[16][520];   // tanh(h) bf16
  const int tid = threadIdx.x;
  const int blk = blockIdx.x;
  const int lane = tid & 63, wave = tid >> 6;
  const int j0 = wave * 64;
  const int lr = lane & 15, lk = lane >> 4;

  // register-resident W: k in [0,64), this wave's 64 j-cols. 32 VGPRs, pinned.
  short8 wreg[4][2];
  #pragma unroll
  for (int jt = 0; jt < 4; ++jt) {
    const short* wrow = Wb + (j0 + jt * 16 + lr) * 512 + lk * 8;
    #pragma unroll
    for (int kt = 0; kt < 2; ++kt) {
      wreg[jt][kt] = *(const short8*)(wrow + kt * 32);
      asm volatile("" : "+v"(wreg[jt][kt]));   // block remat/sink
    }
  }

  // stream row pointers (loop-invariant; kt offsets fold to immediates)
  const short* pj[4];
  #pragma unroll
  for (int jt = 0; jt < 4; ++jt)
    pj[jt] = Wb + (j0 + jt * 16 + lr) * 512 + lk * 8;

  // LDS-resident W slice (k in [64,192)): 512 rows x 16 short8-chunks
  for (int c = 0; c < 16; ++c) {
    int idx = c * 512 + tid;
    int j = idx >> 4, ch = idx & 15;
    *(short8*)&w_lds[j][ch * 8] = *(const short8*)(Wb + j * 512 + 64 + ch * 8);
  }

  float h[4][4];
  #pragma unroll
  for (int jt = 0; jt < 4; ++jt)
    #pragma unroll
    for (int q = 0; q < 4; ++q) h[jt][q] = 0.f;

  const size_t base = (size_t)(blk * 16 + lk * 4) * 524288 + j0 + lr;
  __syncthreads();

  f32x4 acc[4];
  // prologue: acc <- xu[t=0]
  {
    const float* p = out + base;
    #pragma unroll
    for (int jt = 0; jt < 4; ++jt)
      #pragma unroll
      for (int q = 0; q < 4; ++q)
        acc[jt][q] = p[(size_t)q * 524288 + jt * 16];
  }

  for (int t = 0; t < 1024; ++t) {
    // A = tanh(h) -> bf16 staging
    #pragma unroll
    for (int jt = 0; jt < 4; ++jt)
      #pragma unroll
      for (int q = 0; q < 4; ++q)
        a_lds[lk * 4 + q][j0 + jt * 16 + lr] = f2bf(tanh_fast(h[jt][q]));
    __syncthreads();

    // issue first two stream groups (kt 6,7) — consumed after reg+LDS MFMAs
    short8 s0[4], s1[4];
    #pragma unroll
    for (int jt = 0; jt < 4; ++jt) s0[jt] = *(const short8*)(pj[jt] + 6 * 32);
    #pragma unroll
    for (int jt = 0; jt < 4; ++jt) s1[jt] = *(const short8*)(pj[jt] + 7 * 32);

    // kt 0..1: register W
    #pragma unroll
    for (int kt = 0; kt < 2; ++kt) {
      short8 a8 = *(const short8*)&a_lds[lr][kt * 32 + lk * 8];
      #pragma unroll
      for (int jt = 0; jt < 4; ++jt)
        acc[jt] = __builtin_amdgcn_mfma_f32_16x16x32_bf16(a8, wreg[jt][kt], acc[jt], 0, 0, 0);
    }
    // kt 2..5: LDS W
    #pragma unroll
    for (int kt = 2; kt < 6; ++kt) {
      short8 a8 = *(const short8*)&a_lds[lr][kt * 32 + lk * 8];
      #pragma unroll
      for (int jt = 0; jt < 4; ++jt) {
        short8 b = *(const short8*)&w_lds[j0 + jt * 16 + lr][(kt - 2) * 32 + lk * 8];
        acc[jt] = __builtin_amdgcn_mfma_f32_16x16x32_bf16(a8, b, acc[jt], 0, 0, 0);
      }
    }
    // kt 6..15: streamed W, depth-2 double buffer (s0 even, s1 odd)
    #pragma unroll
    for (int kt = 6; kt < 16; ++kt) {
      short8 a8 = *(const short8*)&a_lds[lr][kt * 32 + lk * 8];
      if ((kt & 1) == 0) {
        #pragma unroll
        for (int jt = 0; jt < 4; ++jt)
          acc[jt] = __builtin_amdgcn_mfma_f32_16x16x32_bf16(a8, s0[jt], acc[jt], 0, 0, 0);
        if (kt + 2 < 16) {
          #pragma unroll
          for (int jt = 0; jt < 4; ++jt)
            s0[jt] = *(const short8*)(pj[jt] + (kt + 2) * 32);
        }
      } else {
        #pragma unroll
        for (int jt = 0; jt < 4; ++jt)
          acc[jt] = __builtin_amdgcn_mfma_f32_16x16x32_bf16(a8, s1[jt], acc[jt], 0, 0, 0);
        if (kt + 2 < 16) {
          #pragma unroll
          for (int jt = 0; jt < 4; ++jt)
            s1[jt] = *(const short8*)(pj[jt] + (kt + 2) * 32);
        }
      }
    }

    // h' = 0.9*h + 0.1*acc; store in place over xu[t]
    float* po = out + base + (size_t)t * 512;
    #pragma unroll
    for (int jt = 0; jt < 4; ++jt)
      #pragma unroll
      for (int q = 0; q < 4; ++q) {
        float v = 0.9f * h[jt][q] + 0.1f * acc[jt][q];
        h[jt][q] = v;
        po[(size_t)q * 524288 + jt * 16] = v;
      }
    __syncthreads();  // a_lds reads done before next iteration's writes

    // tail: prefetch next step's xu into acc (hides L3 latency)
    int tn = t + 1; if (tn > 1023) tn = 1023;
    const float* pn = out + base + (size_t)tn * 512;
    #pragma unroll
    for (int jt = 0; jt < 4; ++jt)
      #pragma unroll
      for (int q = 0; q < 4; ++q)
        acc[jt][q] = pn[(size_t)q * 524288 + jt * 16];
  }
}

// ----------------------------------------------------------------
extern "C" void kernel_launch(void* const* d_in, const int* in_sizes, int n_in,
                              void* d_out, int out_size, void* d_ws, size_t ws_size,
                              hipStream_t stream) {
  (void)in_sizes; (void)n_in; (void)out_size; (void)ws_size;
  const float* x = (const float*)d_in[0];
  const float* W = (const float*)d_in[1];
  const float* U = (const float*)d_in[2];
  float* out = (float*)d_out;
  short* Wb = (short*)d_ws;
  short* Ub = Wb + 512 * 512;

  convert_wu<<<384, 256, 0, stream>>>(W, U, Wb, Ub);
  xu_gemm<<<2048, 256, 0, stream>>>(x, Ub, out);
  rnn_scan<<<4, 512, 0, stream>>>(Wb, out);
}